// Round 5
// baseline (596.870 us; speedup 1.0000x reference)
//
#include <hip/hip_runtime.h>
#include <hip/hip_fp16.h>
#include <stdint.h>

#define NNODES 20000
#define EEDGES 320000
#define DD     256
#define NEG_SLOPE 0.2f
#define SCAN_BLOCKS ((NNODES + 255) / 256)
#define ESTR   20480   // padded stride for es/ed partial arrays

typedef _Float16 half8 __attribute__((ext_vector_type(8)));
typedef _Float16 half4 __attribute__((ext_vector_type(4)));
typedef float f32x4 __attribute__((ext_vector_type(4)));

// ---------------- CSR build ----------------

__global__ void zero_ints_k(int* __restrict__ p, int n) {
    int i = blockIdx.x * 256 + threadIdx.x;
    if (i < n) p[i] = 0;
}

__global__ void hist_k(const int* __restrict__ dst, int* __restrict__ rowptr) {
    int i = blockIdx.x * 256 + threadIdx.x;
    if (i < EEDGES) atomicAdd(&rowptr[dst[i] + 1], 1);
}

__global__ __launch_bounds__(256) void scan1_k(int* __restrict__ rowptr, int* __restrict__ bsums) {
    __shared__ int buf[256];
    int idx = blockIdx.x * 256 + threadIdx.x;
    int v = (idx < NNODES) ? rowptr[idx + 1] : 0;
    buf[threadIdx.x] = v;
    __syncthreads();
#pragma unroll
    for (int off = 1; off < 256; off <<= 1) {
        int t = (threadIdx.x >= (unsigned)off) ? buf[threadIdx.x - off] : 0;
        __syncthreads();
        buf[threadIdx.x] += t;
        __syncthreads();
    }
    if (idx < NNODES) rowptr[idx + 1] = buf[threadIdx.x];
    if (threadIdx.x == 255) bsums[blockIdx.x] = buf[255];
}

__global__ __launch_bounds__(128) void scan2_k(int* __restrict__ bsums) {
    __shared__ int buf[128];
    int v = (threadIdx.x < SCAN_BLOCKS) ? bsums[threadIdx.x] : 0;
    buf[threadIdx.x] = v;
    __syncthreads();
#pragma unroll
    for (int off = 1; off < 128; off <<= 1) {
        int t = (threadIdx.x >= (unsigned)off) ? buf[threadIdx.x - off] : 0;
        __syncthreads();
        buf[threadIdx.x] += t;
        __syncthreads();
    }
    if (threadIdx.x < SCAN_BLOCKS) bsums[threadIdx.x] = buf[threadIdx.x];
}

__global__ void scan3_k(int* __restrict__ rowptr, const int* __restrict__ bsums,
                        int* __restrict__ cursor) {
    int idx = blockIdx.x * 256 + threadIdx.x;
    if (idx < NNODES) {
        int v = rowptr[idx + 1];
        if (blockIdx.x > 0) { v += bsums[blockIdx.x - 1]; rowptr[idx + 1] = v; }
        if (idx + 1 < NNODES) cursor[idx + 1] = v;
        if (idx == 0) cursor[0] = 0;
    }
}

__global__ void scatter_k(const int* __restrict__ src, const int* __restrict__ dst,
                          int* __restrict__ cursor, int* __restrict__ colsrc) {
    int i = blockIdx.x * 256 + threadIdx.x;
    if (i < EEDGES) {
        int d = dst[i];
        int pos = atomicAdd(&cursor[d], 1);
        colsrc[pos] = src[i];
    }
}

// ---------------- fp32 -> fp16 hi/lo split (row-major) ----------------

__global__ void cvt_split_k(const float* __restrict__ X, _Float16* __restrict__ Xh,
                            _Float16* __restrict__ Xl, int n) {
    int i = blockIdx.x * 256 + threadIdx.x;
    if (i < n) {
        float v = X[i];
        _Float16 hi = (_Float16)v;
        Xh[i] = hi;
        Xl[i] = (_Float16)(v - (float)hi);
    }
}

// ---------------- all 9 weight conversions in ONE launch (R5) ----------------
// blockIdx.y: 0 = W1 row-major split (slot 0, B^T operand for the W12 fold);
// 1 = W2^T (slot 1); 2..7 = Ws[y-2]^T (slot y); 8 = (W3_top+W3_bot)^T (slot 8).

__global__ void cvt_weights_k(const float* __restrict__ W1, const float* __restrict__ W2,
                              const float* __restrict__ Ws, const float* __restrict__ W3,
                              _Float16* __restrict__ WT) {
    int i = blockIdx.x * 256 + threadIdx.x;
    if (i >= DD * DD) return;
    const size_t WSZ = (size_t)DD * DD;
    int y = blockIdx.y;
    _Float16* Wh = WT + (size_t)y * 2 * WSZ;
    _Float16* Wl = Wh + WSZ;
    if (y == 0) {
        float v = W1[i];
        _Float16 hi = (_Float16)v;
        Wh[i] = hi;
        Wl[i] = (_Float16)(v - (float)hi);
    } else {
        const float* W = (y == 1) ? W2 : (y == 8) ? W3 : (Ws + (size_t)(y - 2) * WSZ);
        int k = i >> 8, n = i & 255;
        float v = W[i];
        if (y == 8) v += W3[i + WSZ];
        _Float16 hi = (_Float16)v;
        Wh[n * DD + k] = hi;
        Wl[n * DD + k] = (_Float16)(v - (float)hi);
    }
}

// ---------------- split-fp16 MFMA GEMM, 64x128 tile, 512 threads ----------------
// R2-proven shape + R5: 1D grid with bijective XCD-chunk swizzle (m204).
// Mechanism: the two col-blocks of each A row-panel were consecutive in
// dispatch order -> round-robin put them on DIFFERENT XCDs, fetching every
// A panel twice over the fabric. Chunked swizzle puts pairs + neighboring
// row-panels on the same XCD L2 -> A fetched ~once per XCD.
// DOTS epilogue (R3-proven): es/ed attention dots from live accumulators.

template<bool OUT_SPLIT, bool DOTS>
__global__ __launch_bounds__(512, 4) void gemm_k(
    const _Float16* __restrict__ Ah, const _Float16* __restrict__ Al,
    const _Float16* __restrict__ Bh, const _Float16* __restrict__ Bl,
    float* __restrict__ C, _Float16* __restrict__ Ch, _Float16* __restrict__ Cl,
    const float* __restrict__ asrc, const float* __restrict__ adst,
    float* __restrict__ esp, float* __restrict__ edp, int M)
{
    // XCD-chunk swizzle (bijective for any nwg): orig%8 = XCD under round-robin
    const int nwg = gridDim.x;
    const int orig = blockIdx.x;
    const int q = nwg >> 3, r = nwg & 7;
    const int xcd = orig & 7, idx = orig >> 3;
    const int sw = (xcd < r ? xcd * (q + 1) : r * (q + 1) + (xcd - r) * q) + idx;
    const int by = sw >> 1;            // row-panel 0..(nwg/2-1)
    const int bx = sw & 1;             // col-block 0..1

    // carve-up (halves): A_h 0..4096, A_l 4096..8192, B_h 8192..16384, B_l 16384..24576
    __shared__ _Float16 smem[24576];
    _Float16* sAh = smem;
    _Float16* sAl = smem + 4096;
    _Float16* sBh = smem + 8192;
    _Float16* sBl = smem + 16384;

    const int t = threadIdx.x;          // 0..511
    const int lane = t & 63;
    const int w = t >> 6;               // 0..7
    const int rowBase = by * 64;
    const int colBase = bx * 128;
    const int mo = (w & 1) * 32;        // wave row offset (2 row-waves)
    const int no = (w >> 1) * 32;       // wave col offset (4 col-waves)

    const int arow = t >> 3;            // 0..63
    const int slot = t & 7;             // 0..7 (16B slots per 64-half row)
    const int swz = (slot ^ (arow & 7)) << 3;   // swizzled half-offset within row

    f32x4 acc[2][2];
#pragma unroll
    for (int m = 0; m < 2; ++m)
#pragma unroll
        for (int n = 0; n < 2; ++n) acc[m][n] = (f32x4){0.f, 0.f, 0.f, 0.f};

    int4 pa_h, pa_l, pb_h0, pb_h1, pb_l0, pb_l1;

#define LOADSTAGE(S) { \
        size_t aoff  = (size_t)(rowBase + arow) * DD + (S) * 64 + slot * 8; \
        size_t boff0 = (size_t)(colBase + arow) * DD + (S) * 64 + slot * 8; \
        size_t boff1 = boff0 + (size_t)64 * DD; \
        pa_h  = *(const int4*)(Ah + aoff); \
        pa_l  = *(const int4*)(Al + aoff); \
        pb_h0 = *(const int4*)(Bh + boff0); \
        pb_h1 = *(const int4*)(Bh + boff1); \
        pb_l0 = *(const int4*)(Bl + boff0); \
        pb_l1 = *(const int4*)(Bl + boff1); \
    }

#define WRITESTAGE() { \
        int da  = arow * 64 + swz; \
        *(int4*)(sAh + da) = pa_h; \
        *(int4*)(sAl + da) = pa_l; \
        *(int4*)(sBh + da) = pb_h0; \
        *(int4*)(sBh + da + 4096) = pb_h1; \
        *(int4*)(sBl + da) = pb_l0; \
        *(int4*)(sBl + da + 4096) = pb_l1; \
    }

    LOADSTAGE(0);
    const int fr = lane & 15;
    const int fq = lane >> 4;

    for (int s = 0; s < 4; ++s) {
        __syncthreads();
        WRITESTAGE();
        __syncthreads();
        if (s < 3) { LOADSTAGE(s + 1); }

#pragma unroll
        for (int kk = 0; kk < 2; ++kk) {
            const int c = kk * 4 + fq;
            half8 ah[2], al[2], bh[2], bl[2];
#pragma unroll
            for (int m = 0; m < 2; ++m) {
                int ra = mo + m * 16 + fr;
                int oa = ra * 64 + ((c ^ (ra & 7)) << 3);
                ah[m] = *(const half8*)(sAh + oa);
                al[m] = *(const half8*)(sAl + oa);
            }
#pragma unroll
            for (int n = 0; n < 2; ++n) {
                int rb = no + n * 16 + fr;
                int ob = rb * 64 + ((c ^ (rb & 7)) << 3);
                bh[n] = *(const half8*)(sBh + ob);
                bl[n] = *(const half8*)(sBl + ob);
            }
#pragma unroll
            for (int m = 0; m < 2; ++m)
#pragma unroll
                for (int n = 0; n < 2; ++n) {
                    acc[m][n] = __builtin_amdgcn_mfma_f32_16x16x32_f16(ah[m], bh[n], acc[m][n], 0, 0, 0);
                    acc[m][n] = __builtin_amdgcn_mfma_f32_16x16x32_f16(ah[m], bl[n], acc[m][n], 0, 0, 0);
                    acc[m][n] = __builtin_amdgcn_mfma_f32_16x16x32_f16(al[m], bh[n], acc[m][n], 0, 0, 0);
                    acc[m][n] = __builtin_amdgcn_mfma_f32_16x16x32_f16(al[m], bl[n], acc[m][n], 0, 0, 0);
                }
        }
    }
#undef LOADSTAGE
#undef WRITESTAGE

    // C/D layout (verified): col = lane&15, row = (lane>>4)*4 + reg
    const int ccol = lane & 15;
    const int crq = (lane >> 4) * 4;

    if constexpr (OUT_SPLIT) {
        // bounce via LDS: pitch 136 halves -> coalesced half8 stores
        __syncthreads();   // all staged-LDS reads done before overwrite
#pragma unroll
        for (int m = 0; m < 2; ++m)
#pragma unroll
            for (int n = 0; n < 2; ++n)
#pragma unroll
                for (int r = 0; r < 4; ++r) {
                    int row = mo + m * 16 + crq + r;        // 0..63
                    int col = no + n * 16 + ccol;           // 0..127
                    float v = acc[m][n][r];
                    _Float16 hi = (_Float16)v;
                    smem[row * 136 + col] = hi;
                    smem[8704 + row * 136 + col] = (_Float16)(v - (float)hi);
                }
        __syncthreads();
#pragma unroll
        for (int i = 0; i < 2; ++i) {
            int slotId = i * 512 + t;         // 0..1023
            int srow = slotId >> 4;           // 0..63
            int sc = slotId & 15;             // 16B chunk within 128-half row
            int grow = rowBase + srow;
            if (grow < M) {
                half8 hv = *(const half8*)(smem + srow * 136 + sc * 8);
                half8 lv = *(const half8*)(smem + 8704 + srow * 136 + sc * 8);
                *(half8*)(Ch + (size_t)grow * DD + colBase + sc * 8) = hv;
                *(half8*)(Cl + (size_t)grow * DD + colBase + sc * 8) = lv;
            }
        }
    } else {
#pragma unroll
        for (int m = 0; m < 2; ++m) {
            int growb = rowBase + mo + m * 16 + crq;
#pragma unroll
            for (int n = 0; n < 2; ++n) {
                int gcol = colBase + no + n * 16 + ccol;
#pragma unroll
                for (int r = 0; r < 4; ++r) {
                    int grow = growb + r;
                    if (grow < M) C[(size_t)grow * DD + gcol] = acc[m][n][r];
                }
            }
        }
    }

    if constexpr (DOTS) {
        // attention dots from live accumulators; per-col-block partial rows
        float as0 = asrc[colBase + no + ccol];
        float as1 = asrc[colBase + no + 16 + ccol];
        float ad0 = adst[colBase + no + ccol];
        float ad1 = adst[colBase + no + 16 + ccol];
        __syncthreads();   // staged-LDS reads complete before scratch reuse
        float* sred = (float*)smem;          // [64][8] es + [64][8] ed = 4KB
        const int cw = w >> 1;               // col-wave 0..3
#pragma unroll
        for (int m = 0; m < 2; ++m)
#pragma unroll
            for (int r = 0; r < 4; ++r) {
                float ps = acc[m][0][r] * as0 + acc[m][1][r] * as1;
                float pd = acc[m][0][r] * ad0 + acc[m][1][r] * ad1;
#pragma unroll
                for (int off = 1; off < 16; off <<= 1) {
                    ps += __shfl_xor(ps, off);
                    pd += __shfl_xor(pd, off);
                }
                if (ccol == 0) {
                    int row = mo + m * 16 + crq + r;   // 0..63
                    sred[row * 8 + cw] = ps;
                    sred[512 + row * 8 + cw] = pd;
                }
            }
        __syncthreads();
        if (t < 64) {
            float esb = sred[t * 8 + 0] + sred[t * 8 + 1] + sred[t * 8 + 2] + sred[t * 8 + 3];
            float edb = sred[512 + t * 8 + 0] + sred[512 + t * 8 + 1]
                      + sred[512 + t * 8 + 2] + sred[512 + t * 8 + 3];
            int grow = rowBase + t;
            if (grow < M) {
                esp[(size_t)bx * ESTR + grow] = esb;
                edp[(size_t)bx * ESTR + grow] = edb;
            }
        }
    }
}

// ---------------- fused segment softmax + aggregation; writes fp16 hi/lo split ----
// R5: TWO waves per node, edge-interleaved. R0/R4 body is latency-bound at
// 3.45 TB/s with VGPR-level ILP collapsed by the compiler (VGPR 36); R2 proved
// the fabric sustains >=4.0 TB/s for this pattern but reg-pipelining costs
// occupancy. So scale TLP: wave h of each node takes 8-edge batches at
// b = h*8, stride 16 (same gather code), partial accs combined via 4KB LDS.
// Softmax is duplicated per wave (L2-hot, cheap). Block 512 = 4 nodes,
// grid 5000 exact, no early returns (block-wide barrier).

template<bool RELU>
__global__ __launch_bounds__(512) void gat_agg_k(const float* __restrict__ hw,
                                                 const float* __restrict__ es0,
                                                 const float* __restrict__ es1,
                                                 const float* __restrict__ ed0,
                                                 const float* __restrict__ ed1,
                                                 const int* __restrict__ rowptr,
                                                 const int* __restrict__ colsrc,
                                                 float* __restrict__ ealpha,
                                                 const float* __restrict__ bias,
                                                 _Float16* __restrict__ hh,
                                                 _Float16* __restrict__ hl) {
    __shared__ float sacc[4][DD];
    const int t = threadIdx.x;
    const int lane = t & 63;
    const int wv = t >> 6;      // 0..7
    const int ni = wv >> 1;     // node-in-block 0..3
    const int h  = wv & 1;      // edge-half 0/1
    const int node = blockIdx.x * 4 + ni;   // grid exactly 5000 -> always < NNODES

    int start = rowptr[node], end = rowptr[node + 1];
    int deg = end - start;
    float edd = ed0[node] + ed1[node];

    float4 acc0 = make_float4(0.f, 0.f, 0.f, 0.f);
    float4 acc1 = acc0, acc2 = acc0, acc3 = acc0;
    float4 acc4 = acc0, acc5 = acc0, acc6 = acc0, acc7 = acc0;

#define FMA4(ACC, W_, V) \
    ACC.x = fmaf(W_, V.x, ACC.x); ACC.y = fmaf(W_, V.y, ACC.y); \
    ACC.z = fmaf(W_, V.z, ACC.z); ACC.w = fmaf(W_, V.w, ACC.w);

    if (deg > 0 && deg <= 64) {
        int j = start + lane;
        bool valid = j < end;
        int msrc = valid ? colsrc[j] : 0;
        float e = valid ? es0[msrc] + es1[msrc] + edd : -INFINITY;
        e = fmaxf(e, NEG_SLOPE * e);
        float mx = e;
#pragma unroll
        for (int off = 32; off; off >>= 1) mx = fmaxf(mx, __shfl_xor(mx, off));
        float ee = valid ? expf(e - mx) : 0.f;
        float sum = ee;
#pragma unroll
        for (int off = 32; off; off >>= 1) sum += __shfl_xor(sum, off);
        float w = ee / sum;

        for (int b = h * 8; b < deg; b += 16) {
            if (deg - b >= 8) {
                int s0 = __shfl(msrc, b + 0), s1 = __shfl(msrc, b + 1);
                int s2 = __shfl(msrc, b + 2), s3 = __shfl(msrc, b + 3);
                int s4 = __shfl(msrc, b + 4), s5 = __shfl(msrc, b + 5);
                int s6 = __shfl(msrc, b + 6), s7 = __shfl(msrc, b + 7);
                float w0 = __shfl(w, b + 0), w1 = __shfl(w, b + 1);
                float w2 = __shfl(w, b + 2), w3 = __shfl(w, b + 3);
                float w4 = __shfl(w, b + 4), w5 = __shfl(w, b + 5);
                float w6 = __shfl(w, b + 6), w7 = __shfl(w, b + 7);
                float4 v0 = *(const float4*)(hw + (size_t)s0 * DD + lane * 4);
                float4 v1 = *(const float4*)(hw + (size_t)s1 * DD + lane * 4);
                float4 v2 = *(const float4*)(hw + (size_t)s2 * DD + lane * 4);
                float4 v3 = *(const float4*)(hw + (size_t)s3 * DD + lane * 4);
                float4 v4 = *(const float4*)(hw + (size_t)s4 * DD + lane * 4);
                float4 v5 = *(const float4*)(hw + (size_t)s5 * DD + lane * 4);
                float4 v6 = *(const float4*)(hw + (size_t)s6 * DD + lane * 4);
                float4 v7 = *(const float4*)(hw + (size_t)s7 * DD + lane * 4);
                FMA4(acc0, w0, v0); FMA4(acc1, w1, v1);
                FMA4(acc2, w2, v2); FMA4(acc3, w3, v3);
                FMA4(acc4, w4, v4); FMA4(acc5, w5, v5);
                FMA4(acc6, w6, v6); FMA4(acc7, w7, v7);
            } else {
                int j2 = b;
                if (j2 + 4 <= deg) {
                    int s0 = __shfl(msrc, j2 + 0), s1 = __shfl(msrc, j2 + 1);
                    int s2 = __shfl(msrc, j2 + 2), s3 = __shfl(msrc, j2 + 3);
                    float w0 = __shfl(w, j2 + 0), w1 = __shfl(w, j2 + 1);
                    float w2 = __shfl(w, j2 + 2), w3 = __shfl(w, j2 + 3);
                    float4 v0 = *(const float4*)(hw + (size_t)s0 * DD + lane * 4);
                    float4 v1 = *(const float4*)(hw + (size_t)s1 * DD + lane * 4);
                    float4 v2 = *(const float4*)(hw + (size_t)s2 * DD + lane * 4);
                    float4 v3 = *(const float4*)(hw + (size_t)s3 * DD + lane * 4);
                    FMA4(acc0, w0, v0); FMA4(acc1, w1, v1);
                    FMA4(acc2, w2, v2); FMA4(acc3, w3, v3);
                    j2 += 4;
                }
                for (; j2 < deg; ++j2) {
                    int   s0 = __shfl(msrc, j2);
                    float w0 = __shfl(w, j2);
                    float4 v0 = *(const float4*)(hw + (size_t)s0 * DD + lane * 4);
                    FMA4(acc0, w0, v0);
                }
            }
        }
    } else if (deg > 64 && h == 0) {
        // rare path (random graph: max deg ~40) — single wave, proven code
        float mx = -INFINITY;
        for (int j = start + lane; j < end; j += 64) {
            int s = colsrc[j];
            float e = es0[s] + es1[s] + edd;
            e = fmaxf(e, NEG_SLOPE * e);
            mx = fmaxf(mx, e);
        }
#pragma unroll
        for (int off = 32; off; off >>= 1) mx = fmaxf(mx, __shfl_xor(mx, off));
        float sum = 0.f;
        for (int j = start + lane; j < end; j += 64) {
            int s = colsrc[j];
            float e = es0[s] + es1[s] + edd;
            e = fmaxf(e, NEG_SLOPE * e);
            float ee = expf(e - mx);
            ealpha[j] = ee;
            sum += ee;
        }
#pragma unroll
        for (int off = 32; off; off >>= 1) sum += __shfl_xor(sum, off);
        float inv = 1.f / sum;
        int j = start;
        for (; j + 4 <= end; j += 4) {
            int s0 = colsrc[j], s1 = colsrc[j + 1], s2 = colsrc[j + 2], s3 = colsrc[j + 3];
            float w0 = ealpha[j] * inv, w1 = ealpha[j + 1] * inv;
            float w2 = ealpha[j + 2] * inv, w3 = ealpha[j + 3] * inv;
            float4 v0 = *(const float4*)(hw + (size_t)s0 * DD + lane * 4);
            float4 v1 = *(const float4*)(hw + (size_t)s1 * DD + lane * 4);
            float4 v2 = *(const float4*)(hw + (size_t)s2 * DD + lane * 4);
            float4 v3 = *(const float4*)(hw + (size_t)s3 * DD + lane * 4);
            FMA4(acc0, w0, v0); FMA4(acc1, w1, v1);
            FMA4(acc2, w2, v2); FMA4(acc3, w3, v3);
        }
        for (; j < end; ++j) {
            int s0 = colsrc[j];
            float w0 = ealpha[j] * inv;
            float4 v0 = *(const float4*)(hw + (size_t)s0 * DD + lane * 4);
            FMA4(acc0, w0, v0);
        }
    }
#undef FMA4

    acc0.x += acc4.x; acc0.y += acc4.y; acc0.z += acc4.z; acc0.w += acc4.w;
    acc1.x += acc5.x; acc1.y += acc5.y; acc1.z += acc5.z; acc1.w += acc5.w;
    acc2.x += acc6.x; acc2.y += acc6.y; acc2.z += acc6.z; acc2.w += acc6.w;
    acc3.x += acc7.x; acc3.y += acc7.y; acc3.z += acc7.z; acc3.w += acc7.w;
    acc0.x += acc1.x; acc0.y += acc1.y; acc0.z += acc1.z; acc0.w += acc1.w;
    acc2.x += acc3.x; acc2.y += acc3.y; acc2.z += acc3.z; acc2.w += acc3.w;
    acc0.x += acc2.x; acc0.y += acc2.y; acc0.z += acc2.z; acc0.w += acc2.w;

    // cross-wave combine: wave1 parks its partial in LDS, wave0 finishes
    if (h == 1) *(float4*)&sacc[ni][lane * 4] = acc0;
    __syncthreads();
    if (h == 0) {
        float4 o = *(const float4*)&sacc[ni][lane * 4];
        acc0.x += o.x; acc0.y += o.y; acc0.z += o.z; acc0.w += o.w;
        float4 b4 = *(const float4*)(bias + lane * 4);
        acc0.x += b4.x; acc0.y += b4.y; acc0.z += b4.z; acc0.w += b4.w;
        if (RELU) {
            acc0.x = fmaxf(acc0.x, 0.f); acc0.y = fmaxf(acc0.y, 0.f);
            acc0.z = fmaxf(acc0.z, 0.f); acc0.w = fmaxf(acc0.w, 0.f);
        }
        size_t base = (size_t)node * DD + lane * 4;
        _Float16 h0 = (_Float16)acc0.x, h1 = (_Float16)acc0.y;
        _Float16 h2 = (_Float16)acc0.z, h3 = (_Float16)acc0.w;
        half4 hv; hv[0] = h0; hv[1] = h1; hv[2] = h2; hv[3] = h3;
        half4 lv;
        lv[0] = (_Float16)(acc0.x - (float)h0); lv[1] = (_Float16)(acc0.y - (float)h1);
        lv[2] = (_Float16)(acc0.z - (float)h2); lv[3] = (_Float16)(acc0.w - (float)h3);
        *(half4*)(hh + base) = hv;
        *(half4*)(hl + base) = lv;
    }
}

// ---------------- driver ----------------

extern "C" void kernel_launch(void* const* d_in, const int* in_sizes, int n_in,
                              void* d_out, int out_size, void* d_ws, size_t ws_size,
                              hipStream_t stream) {
    const float* x     = (const float*)d_in[0];
    const int*   ei    = (const int*)d_in[1];     // [2,E]: src then dst
    const float* W1    = (const float*)d_in[2];
    const float* W2    = (const float*)d_in[3];
    const float* Ws    = (const float*)d_in[4];   // [6,256,256]
    const float* a_src = (const float*)d_in[5];
    const float* a_dst = (const float*)d_in[6];
    const float* bias  = (const float*)d_in[7];
    const float* W3    = (const float*)d_in[8];   // [512,256]
    float* out = (float*)d_out;

    const int* src = ei;
    const int* dst = ei + EEDGES;

    const size_t ND = (size_t)NNODES * DD;

    // workspace carve-up
    float* bufA   = (float*)d_ws;            // ND fp32 (hw)
    float* es01   = bufA + ND;               // 2 * ESTR
    float* ed01   = es01 + 2 * ESTR;         // 2 * ESTR
    float* ealpha = ed01 + 2 * ESTR;         // E
    int*   rowptr = (int*)(ealpha + EEDGES); // N+1
    int*   cursor = rowptr + (NNODES + 1);   // N
    int*   colsrc = cursor + NNODES;         // E
    int*   bsums  = colsrc + EEDGES;         // SCAN_BLOCKS
    _Float16* P0h = (_Float16*)(((uintptr_t)(bsums + SCAN_BLOCKS) + 15) & ~(uintptr_t)15);
    _Float16* P0l = P0h + ND;
    _Float16* P1h = P0l + ND;
    _Float16* P1l = P1h + ND;
    _Float16* WT  = P1l + ND;                // 10 weight pairs (split)
    const size_t WSZ = (size_t)DD * DD;      // 65536

#define WTH(i) (WT + (i) * 2 * WSZ)
#define WTL(i) (WT + (i) * 2 * WSZ + WSZ)

    // --- CSR build ---
    zero_ints_k<<<(NNODES + 1 + 255) / 256, 256, 0, stream>>>(rowptr, NNODES + 1);
    hist_k<<<(EEDGES + 255) / 256, 256, 0, stream>>>(dst, rowptr);
    scan1_k<<<SCAN_BLOCKS, 256, 0, stream>>>(rowptr, bsums);
    scan2_k<<<1, 128, 0, stream>>>(bsums);
    scan3_k<<<SCAN_BLOCKS, 256, 0, stream>>>(rowptr, bsums, cursor);
    scatter_k<<<(EEDGES + 255) / 256, 256, 0, stream>>>(src, dst, cursor, colsrc);

    // --- all 9 weight conversions in one launch ---
    const int WBLK = (DD * DD + 255) / 256;
    cvt_weights_k<<<dim3(WBLK, 9), 256, 0, stream>>>(W1, W2, Ws, W3, WT);

    // --- W12^T fold: C[m][n] = sum_k W2t[m][k] * W1[n][k] = W12^T[m][n], split out ---
    gemm_k<true, false><<<8, 512, 0, stream>>>(WTH(1), WTL(1), WTH(0), WTL(0),
                                               nullptr, WTH(9), WTL(9),
                                               nullptr, nullptr, nullptr, nullptr, DD);

    // --- x split ---
    cvt_split_k<<<(int)((ND + 255) / 256), 256, 0, stream>>>(x, P0h, P0l, (int)ND);

    const int GG = 2 * ((NNODES + 63) / 64);   // 626 blocks, 1D
    const int nodeBlocks = (NNODES + 3) / 4;   // 5000 (exact: 4 nodes/block)

    // h0 = x @ W12 (replaces the two chained x@W1, t@W2 gemms)
    gemm_k<true, false><<<GG, 512, 0, stream>>>(P0h, P0l, WTH(9), WTL(9), nullptr, P1h, P1l,
                                                nullptr, nullptr, nullptr, nullptr, NNODES);

    // 6 GAT layers: h (P1 split) -> hw (bufA fp32) + fused dots -> agg -> h (P1 split)
    for (int l = 0; l < 6; ++l) {
        gemm_k<false, true><<<GG, 512, 0, stream>>>(P1h, P1l, WTH(2 + l), WTL(2 + l),
                                                    bufA, nullptr, nullptr,
                                                    a_src + (size_t)l * DD, a_dst + (size_t)l * DD,
                                                    es01, ed01, NNODES);
        if (l < 5)
            gat_agg_k<false><<<nodeBlocks, 512, 0, stream>>>(bufA, es01, es01 + ESTR,
                                                             ed01, ed01 + ESTR,
                                                             rowptr, colsrc, ealpha,
                                                             bias + (size_t)l * DD, P1h, P1l);
        else
            gat_agg_k<true><<<nodeBlocks, 512, 0, stream>>>(bufA, es01, es01 + ESTR,
                                                            ed01, ed01 + ESTR,
                                                            rowptr, colsrc, ealpha,
                                                            bias + (size_t)l * DD, P1h, P1l);
    }

    // out = relu(h) @ (W3_top + W3_bot)  (relu already applied in layer-5 agg)
    gemm_k<false, false><<<GG, 512, 0, stream>>>(P1h, P1l, WTH(8), WTL(8), out,
                                                 nullptr, nullptr,
                                                 nullptr, nullptr, nullptr, nullptr, NNODES);
#undef WTH
#undef WTL
}

// Round 6
// 567.568 us; speedup vs baseline: 1.0516x; 1.0516x over previous
//
#include <hip/hip_runtime.h>
#include <hip/hip_fp16.h>
#include <stdint.h>

#define NNODES 20000
#define EEDGES 320000
#define DD     256
#define NEG_SLOPE 0.2f
#define SCAN_BLOCKS ((NNODES + 255) / 256)
#define ESTR   20480   // padded stride for es/ed partial arrays

typedef _Float16 half8 __attribute__((ext_vector_type(8)));
typedef _Float16 half4 __attribute__((ext_vector_type(4)));
typedef float f32x4 __attribute__((ext_vector_type(4)));

// ---------------- CSR build ----------------

__global__ void zero_ints_k(int* __restrict__ p, int n) {
    int i = blockIdx.x * 256 + threadIdx.x;
    if (i < n) p[i] = 0;
}

__global__ void hist_k(const int* __restrict__ dst, int* __restrict__ rowptr) {
    int i = blockIdx.x * 256 + threadIdx.x;
    if (i < EEDGES) atomicAdd(&rowptr[dst[i] + 1], 1);
}

__global__ __launch_bounds__(256) void scan1_k(int* __restrict__ rowptr, int* __restrict__ bsums) {
    __shared__ int buf[256];
    int idx = blockIdx.x * 256 + threadIdx.x;
    int v = (idx < NNODES) ? rowptr[idx + 1] : 0;
    buf[threadIdx.x] = v;
    __syncthreads();
#pragma unroll
    for (int off = 1; off < 256; off <<= 1) {
        int t = (threadIdx.x >= (unsigned)off) ? buf[threadIdx.x - off] : 0;
        __syncthreads();
        buf[threadIdx.x] += t;
        __syncthreads();
    }
    if (idx < NNODES) rowptr[idx + 1] = buf[threadIdx.x];
    if (threadIdx.x == 255) bsums[blockIdx.x] = buf[255];
}

__global__ __launch_bounds__(128) void scan2_k(int* __restrict__ bsums) {
    __shared__ int buf[128];
    int v = (threadIdx.x < SCAN_BLOCKS) ? bsums[threadIdx.x] : 0;
    buf[threadIdx.x] = v;
    __syncthreads();
#pragma unroll
    for (int off = 1; off < 128; off <<= 1) {
        int t = (threadIdx.x >= (unsigned)off) ? buf[threadIdx.x - off] : 0;
        __syncthreads();
        buf[threadIdx.x] += t;
        __syncthreads();
    }
    if (threadIdx.x < SCAN_BLOCKS) bsums[threadIdx.x] = buf[threadIdx.x];
}

__global__ void scan3_k(int* __restrict__ rowptr, const int* __restrict__ bsums,
                        int* __restrict__ cursor) {
    int idx = blockIdx.x * 256 + threadIdx.x;
    if (idx < NNODES) {
        int v = rowptr[idx + 1];
        if (blockIdx.x > 0) { v += bsums[blockIdx.x - 1]; rowptr[idx + 1] = v; }
        if (idx + 1 < NNODES) cursor[idx + 1] = v;
        if (idx == 0) cursor[0] = 0;
    }
}

__global__ void scatter_k(const int* __restrict__ src, const int* __restrict__ dst,
                          int* __restrict__ cursor, int* __restrict__ colsrc) {
    int i = blockIdx.x * 256 + threadIdx.x;
    if (i < EEDGES) {
        int d = dst[i];
        int pos = atomicAdd(&cursor[d], 1);
        colsrc[pos] = src[i];
    }
}

// ---------------- all 9 weight conversions in ONE launch ----------------
// blockIdx.y: 0 = W1 row-major split (slot 0, B^T operand for the W12 fold);
// 1 = W2^T (slot 1); 2..7 = Ws[y-2]^T (slot y); 8 = (W3_top+W3_bot)^T (slot 8).

__global__ void cvt_weights_k(const float* __restrict__ W1, const float* __restrict__ W2,
                              const float* __restrict__ Ws, const float* __restrict__ W3,
                              _Float16* __restrict__ WT) {
    int i = blockIdx.x * 256 + threadIdx.x;
    if (i >= DD * DD) return;
    const size_t WSZ = (size_t)DD * DD;
    int y = blockIdx.y;
    _Float16* Wh = WT + (size_t)y * 2 * WSZ;
    _Float16* Wl = Wh + WSZ;
    if (y == 0) {
        float v = W1[i];
        _Float16 hi = (_Float16)v;
        Wh[i] = hi;
        Wl[i] = (_Float16)(v - (float)hi);
    } else {
        const float* W = (y == 1) ? W2 : (y == 8) ? W3 : (Ws + (size_t)(y - 2) * WSZ);
        int k = i >> 8, n = i & 255;
        float v = W[i];
        if (y == 8) v += W3[i + WSZ];
        _Float16 hi = (_Float16)v;
        Wh[n * DD + k] = hi;
        Wl[n * DD + k] = (_Float16)(v - (float)hi);
    }
}

// ---------------- split-fp16 MFMA GEMM, 64x128 tile, 512 threads ----------------
// R2-proven shape + R5 bijective XCD-chunk swizzle (keeps both col-blocks of a
// row-panel on one XCD L2 -> A fetched ~once per XCD).
// R6: A_FP32 path — A is staged from fp32 and hi/lo-split IN-REGISTER during
// LDS staging (identical ops to the old cvt_split_k pass, so bit-identical
// results). hi/lo split is 4B/elem = fp32's 4B -> traffic-neutral, but kills
// the standalone convert pass, lets gemm #1 read x directly, and agg write
// plain fp32. A-side rows clamped to M-1 (A may be the real input buffer).
// DOTS epilogue (R3-proven): es/ed attention dots from live accumulators.

template<bool A_FP32, bool OUT_SPLIT, bool DOTS>
__global__ __launch_bounds__(512, 4) void gemm_k(
    const float* __restrict__ Af,
    const _Float16* __restrict__ Ah, const _Float16* __restrict__ Al,
    const _Float16* __restrict__ Bh, const _Float16* __restrict__ Bl,
    float* __restrict__ C, _Float16* __restrict__ Ch, _Float16* __restrict__ Cl,
    const float* __restrict__ asrc, const float* __restrict__ adst,
    float* __restrict__ esp, float* __restrict__ edp, int M)
{
    // XCD-chunk swizzle (bijective for any nwg): orig%8 = XCD under round-robin
    const int nwg = gridDim.x;
    const int orig = blockIdx.x;
    const int q = nwg >> 3, r = nwg & 7;
    const int xcd = orig & 7, idx = orig >> 3;
    const int sw = (xcd < r ? xcd * (q + 1) : r * (q + 1) + (xcd - r) * q) + idx;
    const int by = sw >> 1;            // row-panel
    const int bx = sw & 1;             // col-block 0..1

    // carve-up (halves): A_h 0..4096, A_l 4096..8192, B_h 8192..16384, B_l 16384..24576
    __shared__ _Float16 smem[24576];
    _Float16* sAh = smem;
    _Float16* sAl = smem + 4096;
    _Float16* sBh = smem + 8192;
    _Float16* sBl = smem + 16384;

    const int t = threadIdx.x;          // 0..511
    const int lane = t & 63;
    const int w = t >> 6;               // 0..7
    const int rowBase = by * 64;
    const int colBase = bx * 128;
    const int mo = (w & 1) * 32;        // wave row offset (2 row-waves)
    const int no = (w >> 1) * 32;       // wave col offset (4 col-waves)

    const int arow = t >> 3;            // 0..63
    const int slot = t & 7;             // 0..7 (16B slots per 64-half row)
    const int swz = (slot ^ (arow & 7)) << 3;   // swizzled half-offset within row

    // clamped A row (A may be a real input buffer with no slack past M)
    const int garow = (rowBase + arow < M) ? (rowBase + arow) : (M - 1);

    f32x4 acc[2][2];
#pragma unroll
    for (int m = 0; m < 2; ++m)
#pragma unroll
        for (int n = 0; n < 2; ++n) acc[m][n] = (f32x4){0.f, 0.f, 0.f, 0.f};

    int4 pa_h, pa_l, pb_h0, pb_h1, pb_l0, pb_l1;
    f32x4 fa0, fa1;

#define LOADSTAGE(S) { \
        size_t aoff  = (size_t)garow * DD + (S) * 64 + slot * 8; \
        size_t boff0 = (size_t)(colBase + arow) * DD + (S) * 64 + slot * 8; \
        size_t boff1 = boff0 + (size_t)64 * DD; \
        if constexpr (A_FP32) { \
            fa0 = *(const f32x4*)(Af + aoff); \
            fa1 = *(const f32x4*)(Af + aoff + 4); \
        } else { \
            pa_h = *(const int4*)(Ah + aoff); \
            pa_l = *(const int4*)(Al + aoff); \
        } \
        pb_h0 = *(const int4*)(Bh + boff0); \
        pb_h1 = *(const int4*)(Bh + boff1); \
        pb_l0 = *(const int4*)(Bl + boff0); \
        pb_l1 = *(const int4*)(Bl + boff1); \
    }

#define WRITESTAGE() { \
        int da  = arow * 64 + swz; \
        if constexpr (A_FP32) { \
            half8 hv, lv; \
            _Pragma("unroll") \
            for (int i = 0; i < 4; ++i) { \
                float v0 = fa0[i]; _Float16 h0 = (_Float16)v0; \
                hv[i] = h0; lv[i] = (_Float16)(v0 - (float)h0); \
                float v1 = fa1[i]; _Float16 h1 = (_Float16)v1; \
                hv[4 + i] = h1; lv[4 + i] = (_Float16)(v1 - (float)h1); \
            } \
            *(half8*)(sAh + da) = hv; \
            *(half8*)(sAl + da) = lv; \
        } else { \
            *(int4*)(sAh + da) = pa_h; \
            *(int4*)(sAl + da) = pa_l; \
        } \
        *(int4*)(sBh + da) = pb_h0; \
        *(int4*)(sBh + da + 4096) = pb_h1; \
        *(int4*)(sBl + da) = pb_l0; \
        *(int4*)(sBl + da + 4096) = pb_l1; \
    }

    LOADSTAGE(0);
    const int fr = lane & 15;
    const int fq = lane >> 4;

    for (int s = 0; s < 4; ++s) {
        __syncthreads();
        WRITESTAGE();
        __syncthreads();
        if (s < 3) { LOADSTAGE(s + 1); }

#pragma unroll
        for (int kk = 0; kk < 2; ++kk) {
            const int c = kk * 4 + fq;
            half8 ah[2], al[2], bh[2], bl[2];
#pragma unroll
            for (int m = 0; m < 2; ++m) {
                int ra = mo + m * 16 + fr;
                int oa = ra * 64 + ((c ^ (ra & 7)) << 3);
                ah[m] = *(const half8*)(sAh + oa);
                al[m] = *(const half8*)(sAl + oa);
            }
#pragma unroll
            for (int n = 0; n < 2; ++n) {
                int rb = no + n * 16 + fr;
                int ob = rb * 64 + ((c ^ (rb & 7)) << 3);
                bh[n] = *(const half8*)(sBh + ob);
                bl[n] = *(const half8*)(sBl + ob);
            }
#pragma unroll
            for (int m = 0; m < 2; ++m)
#pragma unroll
                for (int n = 0; n < 2; ++n) {
                    acc[m][n] = __builtin_amdgcn_mfma_f32_16x16x32_f16(ah[m], bh[n], acc[m][n], 0, 0, 0);
                    acc[m][n] = __builtin_amdgcn_mfma_f32_16x16x32_f16(ah[m], bl[n], acc[m][n], 0, 0, 0);
                    acc[m][n] = __builtin_amdgcn_mfma_f32_16x16x32_f16(al[m], bh[n], acc[m][n], 0, 0, 0);
                    acc[m][n] = __builtin_amdgcn_mfma_f32_16x16x32_f16(al[m], bl[n], acc[m][n], 0, 0, 0);
                }
        }
    }
#undef LOADSTAGE
#undef WRITESTAGE

    // C/D layout (verified): col = lane&15, row = (lane>>4)*4 + reg
    const int ccol = lane & 15;
    const int crq = (lane >> 4) * 4;

    if constexpr (OUT_SPLIT) {
        // bounce via LDS: pitch 136 halves -> coalesced half8 stores
        __syncthreads();   // all staged-LDS reads done before overwrite
#pragma unroll
        for (int m = 0; m < 2; ++m)
#pragma unroll
            for (int n = 0; n < 2; ++n)
#pragma unroll
                for (int r = 0; r < 4; ++r) {
                    int row = mo + m * 16 + crq + r;        // 0..63
                    int col = no + n * 16 + ccol;           // 0..127
                    float v = acc[m][n][r];
                    _Float16 hi = (_Float16)v;
                    smem[row * 136 + col] = hi;
                    smem[8704 + row * 136 + col] = (_Float16)(v - (float)hi);
                }
        __syncthreads();
#pragma unroll
        for (int i = 0; i < 2; ++i) {
            int slotId = i * 512 + t;         // 0..1023
            int srow = slotId >> 4;           // 0..63
            int sc = slotId & 15;             // 16B chunk within 128-half row
            int grow = rowBase + srow;
            if (grow < M) {
                half8 hv = *(const half8*)(smem + srow * 136 + sc * 8);
                half8 lv = *(const half8*)(smem + 8704 + srow * 136 + sc * 8);
                *(half8*)(Ch + (size_t)grow * DD + colBase + sc * 8) = hv;
                *(half8*)(Cl + (size_t)grow * DD + colBase + sc * 8) = lv;
            }
        }
    } else {
#pragma unroll
        for (int m = 0; m < 2; ++m) {
            int growb = rowBase + mo + m * 16 + crq;
#pragma unroll
            for (int n = 0; n < 2; ++n) {
                int gcol = colBase + no + n * 16 + ccol;
#pragma unroll
                for (int r = 0; r < 4; ++r) {
                    int grow = growb + r;
                    if (grow < M) C[(size_t)grow * DD + gcol] = acc[m][n][r];
                }
            }
        }
    }

    if constexpr (DOTS) {
        // attention dots from live accumulators; per-col-block partial rows
        float as0 = asrc[colBase + no + ccol];
        float as1 = asrc[colBase + no + 16 + ccol];
        float ad0 = adst[colBase + no + ccol];
        float ad1 = adst[colBase + no + 16 + ccol];
        __syncthreads();   // staged-LDS reads complete before scratch reuse
        float* sred = (float*)smem;          // [64][8] es + [64][8] ed = 4KB
        const int cw = w >> 1;               // col-wave 0..3
#pragma unroll
        for (int m = 0; m < 2; ++m)
#pragma unroll
            for (int r = 0; r < 4; ++r) {
                float ps = acc[m][0][r] * as0 + acc[m][1][r] * as1;
                float pd = acc[m][0][r] * ad0 + acc[m][1][r] * ad1;
#pragma unroll
                for (int off = 1; off < 16; off <<= 1) {
                    ps += __shfl_xor(ps, off);
                    pd += __shfl_xor(pd, off);
                }
                if (ccol == 0) {
                    int row = mo + m * 16 + crq + r;   // 0..63
                    sred[row * 8 + cw] = ps;
                    sred[512 + row * 8 + cw] = pd;
                }
            }
        __syncthreads();
        if (t < 64) {
            float esb = sred[t * 8 + 0] + sred[t * 8 + 1] + sred[t * 8 + 2] + sred[t * 8 + 3];
            float edb = sred[512 + t * 8 + 0] + sred[512 + t * 8 + 1]
                      + sred[512 + t * 8 + 2] + sred[512 + t * 8 + 3];
            int grow = rowBase + t;
            if (grow < M) {
                esp[(size_t)bx * ESTR + grow] = esb;
                edp[(size_t)bx * ESTR + grow] = edb;
            }
        }
    }
}

// ---------------- fused segment softmax + aggregation; writes fp32 h ----------------
// R6: EXACT R4-proven gather body (46.0 us: VGPR 36, Occ 57-58%, 3.45 TB/s).
// Three A/B rounds (R0/R2/R5) established: 8-deep single-wave loop beats both
// reg-pipelining (occupancy loss) and 2-wave split (no occupancy gain, dup
// softmax) — this gather is MSHR-concurrency x miss-latency pinned at ~3.4TB/s.
// Only change vs R4: output is plain fp32 (gemm now splits A in-register).

template<bool RELU>
__global__ __launch_bounds__(256) void gat_agg_k(const float* __restrict__ hw,
                                                 const float* __restrict__ es0,
                                                 const float* __restrict__ es1,
                                                 const float* __restrict__ ed0,
                                                 const float* __restrict__ ed1,
                                                 const int* __restrict__ rowptr,
                                                 const int* __restrict__ colsrc,
                                                 float* __restrict__ ealpha,
                                                 const float* __restrict__ bias,
                                                 float* __restrict__ hout) {
    int wave = threadIdx.x >> 6;
    int lane = threadIdx.x & 63;
    int node = blockIdx.x * 4 + wave;
    if (node >= NNODES) return;
    int start = rowptr[node], end = rowptr[node + 1];
    int deg = end - start;
    float edd = ed0[node] + ed1[node];

    float4 acc0 = make_float4(0.f, 0.f, 0.f, 0.f);
    float4 acc1 = acc0, acc2 = acc0, acc3 = acc0;
    float4 acc4 = acc0, acc5 = acc0, acc6 = acc0, acc7 = acc0;

#define FMA4(ACC, W_, V) \
    ACC.x = fmaf(W_, V.x, ACC.x); ACC.y = fmaf(W_, V.y, ACC.y); \
    ACC.z = fmaf(W_, V.z, ACC.z); ACC.w = fmaf(W_, V.w, ACC.w);

    if (deg <= 64) {
        if (deg > 0) {
            int j = start + lane;
            bool valid = j < end;
            int msrc = valid ? colsrc[j] : 0;
            float e = valid ? es0[msrc] + es1[msrc] + edd : -INFINITY;
            e = fmaxf(e, NEG_SLOPE * e);
            float mx = e;
#pragma unroll
            for (int off = 32; off; off >>= 1) mx = fmaxf(mx, __shfl_xor(mx, off));
            float ee = valid ? expf(e - mx) : 0.f;
            float sum = ee;
#pragma unroll
            for (int off = 32; off; off >>= 1) sum += __shfl_xor(sum, off);
            float w = ee / sum;

            int j2 = 0;
            for (; j2 + 8 <= deg; j2 += 8) {
                int s0 = __shfl(msrc, j2 + 0), s1 = __shfl(msrc, j2 + 1);
                int s2 = __shfl(msrc, j2 + 2), s3 = __shfl(msrc, j2 + 3);
                int s4 = __shfl(msrc, j2 + 4), s5 = __shfl(msrc, j2 + 5);
                int s6 = __shfl(msrc, j2 + 6), s7 = __shfl(msrc, j2 + 7);
                float w0 = __shfl(w, j2 + 0), w1 = __shfl(w, j2 + 1);
                float w2 = __shfl(w, j2 + 2), w3 = __shfl(w, j2 + 3);
                float w4 = __shfl(w, j2 + 4), w5 = __shfl(w, j2 + 5);
                float w6 = __shfl(w, j2 + 6), w7 = __shfl(w, j2 + 7);
                float4 v0 = *(const float4*)(hw + (size_t)s0 * DD + lane * 4);
                float4 v1 = *(const float4*)(hw + (size_t)s1 * DD + lane * 4);
                float4 v2 = *(const float4*)(hw + (size_t)s2 * DD + lane * 4);
                float4 v3 = *(const float4*)(hw + (size_t)s3 * DD + lane * 4);
                float4 v4 = *(const float4*)(hw + (size_t)s4 * DD + lane * 4);
                float4 v5 = *(const float4*)(hw + (size_t)s5 * DD + lane * 4);
                float4 v6 = *(const float4*)(hw + (size_t)s6 * DD + lane * 4);
                float4 v7 = *(const float4*)(hw + (size_t)s7 * DD + lane * 4);
                FMA4(acc0, w0, v0); FMA4(acc1, w1, v1);
                FMA4(acc2, w2, v2); FMA4(acc3, w3, v3);
                FMA4(acc4, w4, v4); FMA4(acc5, w5, v5);
                FMA4(acc6, w6, v6); FMA4(acc7, w7, v7);
            }
            if (j2 + 4 <= deg) {
                int s0 = __shfl(msrc, j2 + 0), s1 = __shfl(msrc, j2 + 1);
                int s2 = __shfl(msrc, j2 + 2), s3 = __shfl(msrc, j2 + 3);
                float w0 = __shfl(w, j2 + 0), w1 = __shfl(w, j2 + 1);
                float w2 = __shfl(w, j2 + 2), w3 = __shfl(w, j2 + 3);
                float4 v0 = *(const float4*)(hw + (size_t)s0 * DD + lane * 4);
                float4 v1 = *(const float4*)(hw + (size_t)s1 * DD + lane * 4);
                float4 v2 = *(const float4*)(hw + (size_t)s2 * DD + lane * 4);
                float4 v3 = *(const float4*)(hw + (size_t)s3 * DD + lane * 4);
                FMA4(acc0, w0, v0); FMA4(acc1, w1, v1);
                FMA4(acc2, w2, v2); FMA4(acc3, w3, v3);
                j2 += 4;
            }
            for (; j2 < deg; ++j2) {
                int   s0 = __shfl(msrc, j2);
                float w0 = __shfl(w, j2);
                float4 v0 = *(const float4*)(hw + (size_t)s0 * DD + lane * 4);
                FMA4(acc0, w0, v0);
            }
        }
    } else {
        float mx = -INFINITY;
        for (int j = start + lane; j < end; j += 64) {
            int s = colsrc[j];
            float e = es0[s] + es1[s] + edd;
            e = fmaxf(e, NEG_SLOPE * e);
            mx = fmaxf(mx, e);
        }
#pragma unroll
        for (int off = 32; off; off >>= 1) mx = fmaxf(mx, __shfl_xor(mx, off));
        float sum = 0.f;
        for (int j = start + lane; j < end; j += 64) {
            int s = colsrc[j];
            float e = es0[s] + es1[s] + edd;
            e = fmaxf(e, NEG_SLOPE * e);
            float ee = expf(e - mx);
            ealpha[j] = ee;
            sum += ee;
        }
#pragma unroll
        for (int off = 32; off; off >>= 1) sum += __shfl_xor(sum, off);
        float inv = 1.f / sum;
        int j = start;
        for (; j + 4 <= end; j += 4) {
            int s0 = colsrc[j], s1 = colsrc[j + 1], s2 = colsrc[j + 2], s3 = colsrc[j + 3];
            float w0 = ealpha[j] * inv, w1 = ealpha[j + 1] * inv;
            float w2 = ealpha[j + 2] * inv, w3 = ealpha[j + 3] * inv;
            float4 v0 = *(const float4*)(hw + (size_t)s0 * DD + lane * 4);
            float4 v1 = *(const float4*)(hw + (size_t)s1 * DD + lane * 4);
            float4 v2 = *(const float4*)(hw + (size_t)s2 * DD + lane * 4);
            float4 v3 = *(const float4*)(hw + (size_t)s3 * DD + lane * 4);
            FMA4(acc0, w0, v0); FMA4(acc1, w1, v1);
            FMA4(acc2, w2, v2); FMA4(acc3, w3, v3);
        }
        for (; j < end; ++j) {
            int s0 = colsrc[j];
            float w0 = ealpha[j] * inv;
            float4 v0 = *(const float4*)(hw + (size_t)s0 * DD + lane * 4);
            FMA4(acc0, w0, v0);
        }
    }
#undef FMA4

    acc0.x += acc4.x; acc0.y += acc4.y; acc0.z += acc4.z; acc0.w += acc4.w;
    acc1.x += acc5.x; acc1.y += acc5.y; acc1.z += acc5.z; acc1.w += acc5.w;
    acc2.x += acc6.x; acc2.y += acc6.y; acc2.z += acc6.z; acc2.w += acc6.w;
    acc3.x += acc7.x; acc3.y += acc7.y; acc3.z += acc7.z; acc3.w += acc7.w;
    acc0.x += acc1.x; acc0.y += acc1.y; acc0.z += acc1.z; acc0.w += acc1.w;
    acc2.x += acc3.x; acc2.y += acc3.y; acc2.z += acc3.z; acc2.w += acc3.w;
    acc0.x += acc2.x; acc0.y += acc2.y; acc0.z += acc2.z; acc0.w += acc2.w;
    float4 b4 = *(const float4*)(bias + lane * 4);
    acc0.x += b4.x; acc0.y += b4.y; acc0.z += b4.z; acc0.w += b4.w;
    if (RELU) {
        acc0.x = fmaxf(acc0.x, 0.f); acc0.y = fmaxf(acc0.y, 0.f);
        acc0.z = fmaxf(acc0.z, 0.f); acc0.w = fmaxf(acc0.w, 0.f);
    }
    *(float4*)(hout + (size_t)node * DD + lane * 4) = acc0;
}

// ---------------- driver ----------------

extern "C" void kernel_launch(void* const* d_in, const int* in_sizes, int n_in,
                              void* d_out, int out_size, void* d_ws, size_t ws_size,
                              hipStream_t stream) {
    const float* x     = (const float*)d_in[0];
    const int*   ei    = (const int*)d_in[1];     // [2,E]: src then dst
    const float* W1    = (const float*)d_in[2];
    const float* W2    = (const float*)d_in[3];
    const float* Ws    = (const float*)d_in[4];   // [6,256,256]
    const float* a_src = (const float*)d_in[5];
    const float* a_dst = (const float*)d_in[6];
    const float* bias  = (const float*)d_in[7];
    const float* W3    = (const float*)d_in[8];   // [512,256]
    float* out = (float*)d_out;

    const int* src = ei;
    const int* dst = ei + EEDGES;

    const size_t ND = (size_t)NNODES * DD;

    // workspace carve-up
    float* bufA   = (float*)d_ws;            // ND fp32 (hw: gemm out / gather in)
    float* hbuf   = bufA + ND;               // ND fp32 (h: agg out / gemm A in)
    float* es01   = hbuf + ND;               // 2 * ESTR
    float* ed01   = es01 + 2 * ESTR;         // 2 * ESTR
    float* ealpha = ed01 + 2 * ESTR;         // E
    int*   rowptr = (int*)(ealpha + EEDGES); // N+1
    int*   cursor = rowptr + (NNODES + 1);   // N
    int*   colsrc = cursor + NNODES;         // E
    int*   bsums  = colsrc + EEDGES;         // SCAN_BLOCKS
    _Float16* WT  = (_Float16*)(((uintptr_t)(bsums + SCAN_BLOCKS) + 15) & ~(uintptr_t)15);
    const size_t WSZ = (size_t)DD * DD;      // 65536

#define WTH(i) (WT + (i) * 2 * WSZ)
#define WTL(i) (WT + (i) * 2 * WSZ + WSZ)

    // --- CSR build ---
    zero_ints_k<<<(NNODES + 1 + 255) / 256, 256, 0, stream>>>(rowptr, NNODES + 1);
    hist_k<<<(EEDGES + 255) / 256, 256, 0, stream>>>(dst, rowptr);
    scan1_k<<<SCAN_BLOCKS, 256, 0, stream>>>(rowptr, bsums);
    scan2_k<<<1, 128, 0, stream>>>(bsums);
    scan3_k<<<SCAN_BLOCKS, 256, 0, stream>>>(rowptr, bsums, cursor);
    scatter_k<<<(EEDGES + 255) / 256, 256, 0, stream>>>(src, dst, cursor, colsrc);

    // --- all 9 weight conversions in one launch ---
    const int WBLK = (DD * DD + 255) / 256;
    cvt_weights_k<<<dim3(WBLK, 9), 256, 0, stream>>>(W1, W2, Ws, W3, WT);

    // --- W12^T fold: C[m][n] = sum_k W2t[m][k] * W1[n][k] = W12^T[m][n], split out ---
    gemm_k<false, true, false><<<8, 512, 0, stream>>>(nullptr, WTH(1), WTL(1), WTH(0), WTL(0),
                                                      nullptr, WTH(9), WTL(9),
                                                      nullptr, nullptr, nullptr, nullptr, DD);

    const int GG = 2 * ((NNODES + 63) / 64);   // 626 blocks, 1D
    const int nodeBlocks = (NNODES + 3) / 4;

    // h0 = x @ W12 (A = raw fp32 input, split in-register; fp32 C)
    gemm_k<true, false, false><<<GG, 512, 0, stream>>>(x, nullptr, nullptr, WTH(9), WTL(9),
                                                       hbuf, nullptr, nullptr,
                                                       nullptr, nullptr, nullptr, nullptr, NNODES);

    // 6 GAT layers: h (hbuf fp32) -> hw (bufA fp32) + fused dots -> agg -> h (hbuf)
    for (int l = 0; l < 6; ++l) {
        gemm_k<true, false, true><<<GG, 512, 0, stream>>>(hbuf, nullptr, nullptr,
                                                          WTH(2 + l), WTL(2 + l),
                                                          bufA, nullptr, nullptr,
                                                          a_src + (size_t)l * DD, a_dst + (size_t)l * DD,
                                                          es01, ed01, NNODES);
        if (l < 5)
            gat_agg_k<false><<<nodeBlocks, 256, 0, stream>>>(bufA, es01, es01 + ESTR,
                                                             ed01, ed01 + ESTR,
                                                             rowptr, colsrc, ealpha,
                                                             bias + (size_t)l * DD, hbuf);
        else
            gat_agg_k<true><<<nodeBlocks, 256, 0, stream>>>(bufA, es01, es01 + ESTR,
                                                            ed01, ed01 + ESTR,
                                                            rowptr, colsrc, ealpha,
                                                            bias + (size_t)l * DD, hbuf);
    }

    // out = relu(h) @ (W3_top + W3_bot)  (relu already applied in layer-5 agg)
    gemm_k<true, false, false><<<GG, 512, 0, stream>>>(hbuf, nullptr, nullptr, WTH(8), WTL(8),
                                                       out, nullptr, nullptr,
                                                       nullptr, nullptr, nullptr, nullptr, NNODES);
#undef WTH
#undef WTL
}

// Round 7
// 546.741 us; speedup vs baseline: 1.0917x; 1.0381x over previous
//
#include <hip/hip_runtime.h>
#include <hip/hip_fp16.h>
#include <stdint.h>

#define NNODES 20000
#define EEDGES 320000
#define DD     256
#define NEG_SLOPE 0.2f
#define SCAN_BLOCKS ((NNODES + 255) / 256)
#define ESTR   20480   // padded stride for es/ed partial arrays

typedef _Float16 half8 __attribute__((ext_vector_type(8)));
typedef _Float16 half4 __attribute__((ext_vector_type(4)));
typedef float f32x4 __attribute__((ext_vector_type(4)));

// async global->LDS, 16B per lane. LDS dest is wave-uniform base + lane*16
// (our per-lane pointer IS base+lane*16-linear, so both interpretations agree).
#define GLDS16(G, L) __builtin_amdgcn_global_load_lds( \
    (const __attribute__((address_space(1))) unsigned int*)(const void*)(G), \
    (__attribute__((address_space(3))) unsigned int*)(void*)(L), 16, 0, 0)

// ---------------- CSR build ----------------

__global__ void zero_ints_k(int* __restrict__ p, int n) {
    int i = blockIdx.x * 256 + threadIdx.x;
    if (i < n) p[i] = 0;
}

__global__ void hist_k(const int* __restrict__ dst, int* __restrict__ rowptr) {
    int i = blockIdx.x * 256 + threadIdx.x;
    if (i < EEDGES) atomicAdd(&rowptr[dst[i] + 1], 1);
}

__global__ __launch_bounds__(256) void scan1_k(int* __restrict__ rowptr, int* __restrict__ bsums) {
    __shared__ int buf[256];
    int idx = blockIdx.x * 256 + threadIdx.x;
    int v = (idx < NNODES) ? rowptr[idx + 1] : 0;
    buf[threadIdx.x] = v;
    __syncthreads();
#pragma unroll
    for (int off = 1; off < 256; off <<= 1) {
        int t = (threadIdx.x >= (unsigned)off) ? buf[threadIdx.x - off] : 0;
        __syncthreads();
        buf[threadIdx.x] += t;
        __syncthreads();
    }
    if (idx < NNODES) rowptr[idx + 1] = buf[threadIdx.x];
    if (threadIdx.x == 255) bsums[blockIdx.x] = buf[255];
}

__global__ __launch_bounds__(128) void scan2_k(int* __restrict__ bsums) {
    __shared__ int buf[128];
    int v = (threadIdx.x < SCAN_BLOCKS) ? bsums[threadIdx.x] : 0;
    buf[threadIdx.x] = v;
    __syncthreads();
#pragma unroll
    for (int off = 1; off < 128; off <<= 1) {
        int t = (threadIdx.x >= (unsigned)off) ? buf[threadIdx.x - off] : 0;
        __syncthreads();
        buf[threadIdx.x] += t;
        __syncthreads();
    }
    if (threadIdx.x < SCAN_BLOCKS) bsums[threadIdx.x] = buf[threadIdx.x];
}

__global__ void scan3_k(int* __restrict__ rowptr, const int* __restrict__ bsums,
                        int* __restrict__ cursor) {
    int idx = blockIdx.x * 256 + threadIdx.x;
    if (idx < NNODES) {
        int v = rowptr[idx + 1];
        if (blockIdx.x > 0) { v += bsums[blockIdx.x - 1]; rowptr[idx + 1] = v; }
        if (idx + 1 < NNODES) cursor[idx + 1] = v;
        if (idx == 0) cursor[0] = 0;
    }
}

__global__ void scatter_k(const int* __restrict__ src, const int* __restrict__ dst,
                          int* __restrict__ cursor, int* __restrict__ colsrc) {
    int i = blockIdx.x * 256 + threadIdx.x;
    if (i < EEDGES) {
        int d = dst[i];
        int pos = atomicAdd(&cursor[d], 1);
        colsrc[pos] = src[i];
    }
}

// ---------------- all 9 weight conversions in ONE launch ----------------
// blockIdx.y: 0 = W1 row-major split (slot 0, B^T operand for the W12 fold);
// 1 = W2^T (slot 1); 2..7 = Ws[y-2]^T (slot y); 8 = (W3_top+W3_bot)^T (slot 8).

__global__ void cvt_weights_k(const float* __restrict__ W1, const float* __restrict__ W2,
                              const float* __restrict__ Ws, const float* __restrict__ W3,
                              _Float16* __restrict__ WT) {
    int i = blockIdx.x * 256 + threadIdx.x;
    if (i >= DD * DD) return;
    const size_t WSZ = (size_t)DD * DD;
    int y = blockIdx.y;
    _Float16* Wh = WT + (size_t)y * 2 * WSZ;
    _Float16* Wl = Wh + WSZ;
    if (y == 0) {
        float v = W1[i];
        _Float16 hi = (_Float16)v;
        Wh[i] = hi;
        Wl[i] = (_Float16)(v - (float)hi);
    } else {
        const float* W = (y == 1) ? W2 : (y == 8) ? W3 : (Ws + (size_t)(y - 2) * WSZ);
        int k = i >> 8, n = i & 255;
        float v = W[i];
        if (y == 8) v += W3[i + WSZ];
        _Float16 hi = (_Float16)v;
        Wh[n * DD + k] = hi;
        Wl[n * DD + k] = (_Float16)(v - (float)hi);
    }
}

// ---------------- split-fp16 MFMA GEMM, 64x128 tile, 512 threads ----------------
// R2-proven shape + R5 bijective XCD-chunk swizzle. R6 A_FP32 in-reg split.
// R7: (a) 3-product split — al*bl dropped (bounded by K*2^-22*|a||b| ~ 1e-8,
// invisible vs the 2^-20 output rounding floor). (b) B staged via
// global_load_lds 16B direct-to-LDS: linear LDS dest (per-lane ptr = wave
// base + lane*16), XOR swizzle moved to the GLOBAL source address (involution
// -> reads unchanged). Kills 4 reg loads + 4 ds_writes per thread per stage.
// DOTS epilogue (R3-proven): es/ed attention dots from live accumulators.

template<bool A_FP32, bool OUT_SPLIT, bool DOTS>
__global__ __launch_bounds__(512, 4) void gemm_k(
    const float* __restrict__ Af,
    const _Float16* __restrict__ Ah, const _Float16* __restrict__ Al,
    const _Float16* __restrict__ Bh, const _Float16* __restrict__ Bl,
    float* __restrict__ C, _Float16* __restrict__ Ch, _Float16* __restrict__ Cl,
    const float* __restrict__ asrc, const float* __restrict__ adst,
    float* __restrict__ esp, float* __restrict__ edp, int M)
{
    // XCD-chunk swizzle (bijective for any nwg): orig%8 = XCD under round-robin
    const int nwg = gridDim.x;
    const int orig = blockIdx.x;
    const int q = nwg >> 3, r = nwg & 7;
    const int xcd = orig & 7, idx = orig >> 3;
    const int sw = (xcd < r ? xcd * (q + 1) : r * (q + 1) + (xcd - r) * q) + idx;
    const int by = sw >> 1;            // row-panel
    const int bx = sw & 1;             // col-block 0..1

    // carve-up (halves): A_h 0..4096, A_l 4096..8192, B_h 8192..16384, B_l 16384..24576
    __shared__ _Float16 smem[24576];
    _Float16* sAh = smem;
    _Float16* sAl = smem + 4096;
    _Float16* sBh = smem + 8192;
    _Float16* sBl = smem + 16384;

    const int t = threadIdx.x;          // 0..511
    const int lane = t & 63;
    const int w = t >> 6;               // 0..7
    const int rowBase = by * 64;
    const int colBase = bx * 128;
    const int mo = (w & 1) * 32;        // wave row offset (2 row-waves)
    const int no = (w >> 1) * 32;       // wave col offset (4 col-waves)

    const int arow = t >> 3;            // 0..63
    const int slot = t & 7;             // 0..7 (16B slots per 64-half row)
    const int swz = (slot ^ (arow & 7)) << 3;   // swizzled half-offset within row

    // clamped A row (A may be a real input buffer with no slack past M)
    const int garow = (rowBase + arow < M) ? (rowBase + arow) : (M - 1);

    f32x4 acc[2][2];
#pragma unroll
    for (int m = 0; m < 2; ++m)
#pragma unroll
        for (int n = 0; n < 2; ++n) acc[m][n] = (f32x4){0.f, 0.f, 0.f, 0.f};

    int4 pa_h, pa_l;
    f32x4 fa0, fa1;

    // A register prefetch (fp32 path splits in-register at WRITESTAGE_A)
#define LOADSTAGE_A(S) { \
        size_t aoff = (size_t)garow * DD + (S) * 64 + slot * 8; \
        if constexpr (A_FP32) { \
            fa0 = *(const f32x4*)(Af + aoff); \
            fa1 = *(const f32x4*)(Af + aoff + 4); \
        } else { \
            pa_h = *(const int4*)(Ah + aoff); \
            pa_l = *(const int4*)(Al + aoff); \
        } \
    }

#define WRITESTAGE_A() { \
        int da = arow * 64 + swz; \
        if constexpr (A_FP32) { \
            half8 hv, lv; \
            _Pragma("unroll") \
            for (int i = 0; i < 4; ++i) { \
                float v0 = fa0[i]; _Float16 h0 = (_Float16)v0; \
                hv[i] = h0; lv[i] = (_Float16)(v0 - (float)h0); \
                float v1 = fa1[i]; _Float16 h1 = (_Float16)v1; \
                hv[4 + i] = h1; lv[4 + i] = (_Float16)(v1 - (float)h1); \
            } \
            *(half8*)(sAh + da) = hv; \
            *(half8*)(sAl + da) = lv; \
        } else { \
            *(int4*)(sAh + da) = pa_h; \
            *(int4*)(sAl + da) = pa_l; \
        } \
    }

    // B direct-to-LDS: linear dest (t*8 halves = wave base + lane*16B),
    // source address carries the XOR swizzle (inverse == forward, involution).
#define GLDS_B(S) { \
        size_t bsw0 = (size_t)(colBase + arow) * DD + (S) * 64 + swz; \
        size_t bsw1 = bsw0 + (size_t)64 * DD; \
        GLDS16(Bh + bsw0, sBh + t * 8); \
        GLDS16(Bh + bsw1, sBh + 4096 + t * 8); \
        GLDS16(Bl + bsw0, sBl + t * 8); \
        GLDS16(Bl + bsw1, sBl + 4096 + t * 8); \
    }

    LOADSTAGE_A(0);
    const int fr = lane & 15;
    const int fq = lane >> 4;

    for (int s = 0; s < 4; ++s) {
        __syncthreads();
        GLDS_B(s);                     // async; drained by next barrier
        WRITESTAGE_A();
        __syncthreads();
        if (s < 3) { LOADSTAGE_A(s + 1); }

#pragma unroll
        for (int kk = 0; kk < 2; ++kk) {
            const int c = kk * 4 + fq;
            half8 ah[2], al[2], bh[2], bl[2];
#pragma unroll
            for (int m = 0; m < 2; ++m) {
                int ra = mo + m * 16 + fr;
                int oa = ra * 64 + ((c ^ (ra & 7)) << 3);
                ah[m] = *(const half8*)(sAh + oa);
                al[m] = *(const half8*)(sAl + oa);
            }
#pragma unroll
            for (int n = 0; n < 2; ++n) {
                int rb = no + n * 16 + fr;
                int ob = rb * 64 + ((c ^ (rb & 7)) << 3);
                bh[n] = *(const half8*)(sBh + ob);
                bl[n] = *(const half8*)(sBl + ob);
            }
#pragma unroll
            for (int m = 0; m < 2; ++m)
#pragma unroll
                for (int n = 0; n < 2; ++n) {
                    acc[m][n] = __builtin_amdgcn_mfma_f32_16x16x32_f16(ah[m], bh[n], acc[m][n], 0, 0, 0);
                    acc[m][n] = __builtin_amdgcn_mfma_f32_16x16x32_f16(ah[m], bl[n], acc[m][n], 0, 0, 0);
                    acc[m][n] = __builtin_amdgcn_mfma_f32_16x16x32_f16(al[m], bh[n], acc[m][n], 0, 0, 0);
                    // al*bl dropped (3-product split): contribution ~1e-8, see header
                }
        }
    }
#undef LOADSTAGE_A
#undef WRITESTAGE_A
#undef GLDS_B

    // C/D layout (verified): col = lane&15, row = (lane>>4)*4 + reg
    const int ccol = lane & 15;
    const int crq = (lane >> 4) * 4;

    if constexpr (OUT_SPLIT) {
        // bounce via LDS: pitch 136 halves -> coalesced half8 stores
        __syncthreads();   // all staged-LDS reads done before overwrite
#pragma unroll
        for (int m = 0; m < 2; ++m)
#pragma unroll
            for (int n = 0; n < 2; ++n)
#pragma unroll
                for (int r = 0; r < 4; ++r) {
                    int row = mo + m * 16 + crq + r;        // 0..63
                    int col = no + n * 16 + ccol;           // 0..127
                    float v = acc[m][n][r];
                    _Float16 hi = (_Float16)v;
                    smem[row * 136 + col] = hi;
                    smem[8704 + row * 136 + col] = (_Float16)(v - (float)hi);
                }
        __syncthreads();
#pragma unroll
        for (int i = 0; i < 2; ++i) {
            int slotId = i * 512 + t;         // 0..1023
            int srow = slotId >> 4;           // 0..63
            int sc = slotId & 15;             // 16B chunk within 128-half row
            int grow = rowBase + srow;
            if (grow < M) {
                half8 hv = *(const half8*)(smem + srow * 136 + sc * 8);
                half8 lv = *(const half8*)(smem + 8704 + srow * 136 + sc * 8);
                *(half8*)(Ch + (size_t)grow * DD + colBase + sc * 8) = hv;
                *(half8*)(Cl + (size_t)grow * DD + colBase + sc * 8) = lv;
            }
        }
    } else {
#pragma unroll
        for (int m = 0; m < 2; ++m) {
            int growb = rowBase + mo + m * 16 + crq;
#pragma unroll
            for (int n = 0; n < 2; ++n) {
                int gcol = colBase + no + n * 16 + ccol;
#pragma unroll
                for (int r = 0; r < 4; ++r) {
                    int grow = growb + r;
                    if (grow < M) C[(size_t)grow * DD + gcol] = acc[m][n][r];
                }
            }
        }
    }

    if constexpr (DOTS) {
        // attention dots from live accumulators; per-col-block partial rows
        float as0 = asrc[colBase + no + ccol];
        float as1 = asrc[colBase + no + 16 + ccol];
        float ad0 = adst[colBase + no + ccol];
        float ad1 = adst[colBase + no + 16 + ccol];
        __syncthreads();   // staged-LDS reads complete before scratch reuse
        float* sred = (float*)smem;          // [64][8] es + [64][8] ed = 4KB
        const int cw = w >> 1;               // col-wave 0..3
#pragma unroll
        for (int m = 0; m < 2; ++m)
#pragma unroll
            for (int r = 0; r < 4; ++r) {
                float ps = acc[m][0][r] * as0 + acc[m][1][r] * as1;
                float pd = acc[m][0][r] * ad0 + acc[m][1][r] * ad1;
#pragma unroll
                for (int off = 1; off < 16; off <<= 1) {
                    ps += __shfl_xor(ps, off);
                    pd += __shfl_xor(pd, off);
                }
                if (ccol == 0) {
                    int row = mo + m * 16 + crq + r;   // 0..63
                    sred[row * 8 + cw] = ps;
                    sred[512 + row * 8 + cw] = pd;
                }
            }
        __syncthreads();
        if (t < 64) {
            float esb = sred[t * 8 + 0] + sred[t * 8 + 1] + sred[t * 8 + 2] + sred[t * 8 + 3];
            float edb = sred[512 + t * 8 + 0] + sred[512 + t * 8 + 1]
                      + sred[512 + t * 8 + 2] + sred[512 + t * 8 + 3];
            int grow = rowBase + t;
            if (grow < M) {
                esp[(size_t)bx * ESTR + grow] = esb;
                edp[(size_t)bx * ESTR + grow] = edb;
            }
        }
    }
}

// ---------------- fused segment softmax + aggregation; writes fp32 h ----------------
// R4/R6-proven gather body (46.0 us: VGPR 36, Occ 57-58%, 3.45 TB/s).
// Three A/B rounds (R0/R2/R5) established the simple 8-deep single-wave loop
// as champion; pattern is pinned ~3.4 TB/s (fabric ceiling for random 1KB-row
// gather). Do not touch.

template<bool RELU>
__global__ __launch_bounds__(256) void gat_agg_k(const float* __restrict__ hw,
                                                 const float* __restrict__ es0,
                                                 const float* __restrict__ es1,
                                                 const float* __restrict__ ed0,
                                                 const float* __restrict__ ed1,
                                                 const int* __restrict__ rowptr,
                                                 const int* __restrict__ colsrc,
                                                 float* __restrict__ ealpha,
                                                 const float* __restrict__ bias,
                                                 float* __restrict__ hout) {
    int wave = threadIdx.x >> 6;
    int lane = threadIdx.x & 63;
    int node = blockIdx.x * 4 + wave;
    if (node >= NNODES) return;
    int start = rowptr[node], end = rowptr[node + 1];
    int deg = end - start;
    float edd = ed0[node] + ed1[node];

    float4 acc0 = make_float4(0.f, 0.f, 0.f, 0.f);
    float4 acc1 = acc0, acc2 = acc0, acc3 = acc0;
    float4 acc4 = acc0, acc5 = acc0, acc6 = acc0, acc7 = acc0;

#define FMA4(ACC, W_, V) \
    ACC.x = fmaf(W_, V.x, ACC.x); ACC.y = fmaf(W_, V.y, ACC.y); \
    ACC.z = fmaf(W_, V.z, ACC.z); ACC.w = fmaf(W_, V.w, ACC.w);

    if (deg <= 64) {
        if (deg > 0) {
            int j = start + lane;
            bool valid = j < end;
            int msrc = valid ? colsrc[j] : 0;
            float e = valid ? es0[msrc] + es1[msrc] + edd : -INFINITY;
            e = fmaxf(e, NEG_SLOPE * e);
            float mx = e;
#pragma unroll
            for (int off = 32; off; off >>= 1) mx = fmaxf(mx, __shfl_xor(mx, off));
            float ee = valid ? expf(e - mx) : 0.f;
            float sum = ee;
#pragma unroll
            for (int off = 32; off; off >>= 1) sum += __shfl_xor(sum, off);
            float w = ee / sum;

            int j2 = 0;
            for (; j2 + 8 <= deg; j2 += 8) {
                int s0 = __shfl(msrc, j2 + 0), s1 = __shfl(msrc, j2 + 1);
                int s2 = __shfl(msrc, j2 + 2), s3 = __shfl(msrc, j2 + 3);
                int s4 = __shfl(msrc, j2 + 4), s5 = __shfl(msrc, j2 + 5);
                int s6 = __shfl(msrc, j2 + 6), s7 = __shfl(msrc, j2 + 7);
                float w0 = __shfl(w, j2 + 0), w1 = __shfl(w, j2 + 1);
                float w2 = __shfl(w, j2 + 2), w3 = __shfl(w, j2 + 3);
                float w4 = __shfl(w, j2 + 4), w5 = __shfl(w, j2 + 5);
                float w6 = __shfl(w, j2 + 6), w7 = __shfl(w, j2 + 7);
                float4 v0 = *(const float4*)(hw + (size_t)s0 * DD + lane * 4);
                float4 v1 = *(const float4*)(hw + (size_t)s1 * DD + lane * 4);
                float4 v2 = *(const float4*)(hw + (size_t)s2 * DD + lane * 4);
                float4 v3 = *(const float4*)(hw + (size_t)s3 * DD + lane * 4);
                float4 v4 = *(const float4*)(hw + (size_t)s4 * DD + lane * 4);
                float4 v5 = *(const float4*)(hw + (size_t)s5 * DD + lane * 4);
                float4 v6 = *(const float4*)(hw + (size_t)s6 * DD + lane * 4);
                float4 v7 = *(const float4*)(hw + (size_t)s7 * DD + lane * 4);
                FMA4(acc0, w0, v0); FMA4(acc1, w1, v1);
                FMA4(acc2, w2, v2); FMA4(acc3, w3, v3);
                FMA4(acc4, w4, v4); FMA4(acc5, w5, v5);
                FMA4(acc6, w6, v6); FMA4(acc7, w7, v7);
            }
            if (j2 + 4 <= deg) {
                int s0 = __shfl(msrc, j2 + 0), s1 = __shfl(msrc, j2 + 1);
                int s2 = __shfl(msrc, j2 + 2), s3 = __shfl(msrc, j2 + 3);
                float w0 = __shfl(w, j2 + 0), w1 = __shfl(w, j2 + 1);
                float w2 = __shfl(w, j2 + 2), w3 = __shfl(w, j2 + 3);
                float4 v0 = *(const float4*)(hw + (size_t)s0 * DD + lane * 4);
                float4 v1 = *(const float4*)(hw + (size_t)s1 * DD + lane * 4);
                float4 v2 = *(const float4*)(hw + (size_t)s2 * DD + lane * 4);
                float4 v3 = *(const float4*)(hw + (size_t)s3 * DD + lane * 4);
                FMA4(acc0, w0, v0); FMA4(acc1, w1, v1);
                FMA4(acc2, w2, v2); FMA4(acc3, w3, v3);
                j2 += 4;
            }
            for (; j2 < deg; ++j2) {
                int   s0 = __shfl(msrc, j2);
                float w0 = __shfl(w, j2);
                float4 v0 = *(const float4*)(hw + (size_t)s0 * DD + lane * 4);
                FMA4(acc0, w0, v0);
            }
        }
    } else {
        float mx = -INFINITY;
        for (int j = start + lane; j < end; j += 64) {
            int s = colsrc[j];
            float e = es0[s] + es1[s] + edd;
            e = fmaxf(e, NEG_SLOPE * e);
            mx = fmaxf(mx, e);
        }
#pragma unroll
        for (int off = 32; off; off >>= 1) mx = fmaxf(mx, __shfl_xor(mx, off));
        float sum = 0.f;
        for (int j = start + lane; j < end; j += 64) {
            int s = colsrc[j];
            float e = es0[s] + es1[s] + edd;
            e = fmaxf(e, NEG_SLOPE * e);
            float ee = expf(e - mx);
            ealpha[j] = ee;
            sum += ee;
        }
#pragma unroll
        for (int off = 32; off; off >>= 1) sum += __shfl_xor(sum, off);
        float inv = 1.f / sum;
        int j = start;
        for (; j + 4 <= end; j += 4) {
            int s0 = colsrc[j], s1 = colsrc[j + 1], s2 = colsrc[j + 2], s3 = colsrc[j + 3];
            float w0 = ealpha[j] * inv, w1 = ealpha[j + 1] * inv;
            float w2 = ealpha[j + 2] * inv, w3 = ealpha[j + 3] * inv;
            float4 v0 = *(const float4*)(hw + (size_t)s0 * DD + lane * 4);
            float4 v1 = *(const float4*)(hw + (size_t)s1 * DD + lane * 4);
            float4 v2 = *(const float4*)(hw + (size_t)s2 * DD + lane * 4);
            float4 v3 = *(const float4*)(hw + (size_t)s3 * DD + lane * 4);
            FMA4(acc0, w0, v0); FMA4(acc1, w1, v1);
            FMA4(acc2, w2, v2); FMA4(acc3, w3, v3);
        }
        for (; j < end; ++j) {
            int s0 = colsrc[j];
            float w0 = ealpha[j] * inv;
            float4 v0 = *(const float4*)(hw + (size_t)s0 * DD + lane * 4);
            FMA4(acc0, w0, v0);
        }
    }
#undef FMA4

    acc0.x += acc4.x; acc0.y += acc4.y; acc0.z += acc4.z; acc0.w += acc4.w;
    acc1.x += acc5.x; acc1.y += acc5.y; acc1.z += acc5.z; acc1.w += acc5.w;
    acc2.x += acc6.x; acc2.y += acc6.y; acc2.z += acc6.z; acc2.w += acc6.w;
    acc3.x += acc7.x; acc3.y += acc7.y; acc3.z += acc7.z; acc3.w += acc7.w;
    acc0.x += acc1.x; acc0.y += acc1.y; acc0.z += acc1.z; acc0.w += acc1.w;
    acc2.x += acc3.x; acc2.y += acc3.y; acc2.z += acc3.z; acc2.w += acc3.w;
    acc0.x += acc2.x; acc0.y += acc2.y; acc0.z += acc2.z; acc0.w += acc2.w;
    float4 b4 = *(const float4*)(bias + lane * 4);
    acc0.x += b4.x; acc0.y += b4.y; acc0.z += b4.z; acc0.w += b4.w;
    if (RELU) {
        acc0.x = fmaxf(acc0.x, 0.f); acc0.y = fmaxf(acc0.y, 0.f);
        acc0.z = fmaxf(acc0.z, 0.f); acc0.w = fmaxf(acc0.w, 0.f);
    }
    *(float4*)(hout + (size_t)node * DD + lane * 4) = acc0;
}

// ---------------- driver ----------------

extern "C" void kernel_launch(void* const* d_in, const int* in_sizes, int n_in,
                              void* d_out, int out_size, void* d_ws, size_t ws_size,
                              hipStream_t stream) {
    const float* x     = (const float*)d_in[0];
    const int*   ei    = (const int*)d_in[1];     // [2,E]: src then dst
    const float* W1    = (const float*)d_in[2];
    const float* W2    = (const float*)d_in[3];
    const float* Ws    = (const float*)d_in[4];   // [6,256,256]
    const float* a_src = (const float*)d_in[5];
    const float* a_dst = (const float*)d_in[6];
    const float* bias  = (const float*)d_in[7];
    const float* W3    = (const float*)d_in[8];   // [512,256]
    float* out = (float*)d_out;

    const int* src = ei;
    const int* dst = ei + EEDGES;

    const size_t ND = (size_t)NNODES * DD;

    // workspace carve-up
    float* bufA   = (float*)d_ws;            // ND fp32 (hw: gemm out / gather in)
    float* hbuf   = bufA + ND;               // ND fp32 (h: agg out / gemm A in)
    float* es01   = hbuf + ND;               // 2 * ESTR
    float* ed01   = es01 + 2 * ESTR;         // 2 * ESTR
    float* ealpha = ed01 + 2 * ESTR;         // E
    int*   rowptr = (int*)(ealpha + EEDGES); // N+1
    int*   cursor = rowptr + (NNODES + 1);   // N
    int*   colsrc = cursor + NNODES;         // E
    int*   bsums  = colsrc + EEDGES;         // SCAN_BLOCKS
    _Float16* WT  = (_Float16*)(((uintptr_t)(bsums + SCAN_BLOCKS) + 15) & ~(uintptr_t)15);
    const size_t WSZ = (size_t)DD * DD;      // 65536

#define WTH(i) (WT + (i) * 2 * WSZ)
#define WTL(i) (WT + (i) * 2 * WSZ + WSZ)

    // --- CSR build ---
    zero_ints_k<<<(NNODES + 1 + 255) / 256, 256, 0, stream>>>(rowptr, NNODES + 1);
    hist_k<<<(EEDGES + 255) / 256, 256, 0, stream>>>(dst, rowptr);
    scan1_k<<<SCAN_BLOCKS, 256, 0, stream>>>(rowptr, bsums);
    scan2_k<<<1, 128, 0, stream>>>(bsums);
    scan3_k<<<SCAN_BLOCKS, 256, 0, stream>>>(rowptr, bsums, cursor);
    scatter_k<<<(EEDGES + 255) / 256, 256, 0, stream>>>(src, dst, cursor, colsrc);

    // --- all 9 weight conversions in one launch ---
    const int WBLK = (DD * DD + 255) / 256;
    cvt_weights_k<<<dim3(WBLK, 9), 256, 0, stream>>>(W1, W2, Ws, W3, WT);

    // --- W12^T fold: C[m][n] = sum_k W2t[m][k] * W1[n][k] = W12^T[m][n], split out ---
    gemm_k<false, true, false><<<8, 512, 0, stream>>>(nullptr, WTH(1), WTL(1), WTH(0), WTL(0),
                                                      nullptr, WTH(9), WTL(9),
                                                      nullptr, nullptr, nullptr, nullptr, DD);

    const int GG = 2 * ((NNODES + 63) / 64);   // 626 blocks, 1D
    const int nodeBlocks = (NNODES + 3) / 4;

    // h0 = x @ W12 (A = raw fp32 input, split in-register; fp32 C)
    gemm_k<true, false, false><<<GG, 512, 0, stream>>>(x, nullptr, nullptr, WTH(9), WTL(9),
                                                       hbuf, nullptr, nullptr,
                                                       nullptr, nullptr, nullptr, nullptr, NNODES);

    // 6 GAT layers: h (hbuf fp32) -> hw (bufA fp32) + fused dots -> agg -> h (hbuf)
    for (int l = 0; l < 6; ++l) {
        gemm_k<true, false, true><<<GG, 512, 0, stream>>>(hbuf, nullptr, nullptr,
                                                          WTH(2 + l), WTL(2 + l),
                                                          bufA, nullptr, nullptr,
                                                          a_src + (size_t)l * DD, a_dst + (size_t)l * DD,
                                                          es01, ed01, NNODES);
        if (l < 5)
            gat_agg_k<false><<<nodeBlocks, 256, 0, stream>>>(bufA, es01, es01 + ESTR,
                                                             ed01, ed01 + ESTR,
                                                             rowptr, colsrc, ealpha,
                                                             bias + (size_t)l * DD, hbuf);
        else
            gat_agg_k<true><<<nodeBlocks, 256, 0, stream>>>(bufA, es01, es01 + ESTR,
                                                            ed01, ed01 + ESTR,
                                                            rowptr, colsrc, ealpha,
                                                            bias + (size_t)l * DD, hbuf);
    }

    // out = relu(h) @ (W3_top + W3_bot)  (relu already applied in layer-5 agg)
    gemm_k<true, false, false><<<GG, 512, 0, stream>>>(hbuf, nullptr, nullptr, WTH(8), WTL(8),
                                                       out, nullptr, nullptr,
                                                       nullptr, nullptr, nullptr, nullptr, NNODES);
#undef WTH
#undef WTL
}